// Round 5
// baseline (753.330 us; speedup 1.0000x reference)
//
#include <hip/hip_runtime.h>
#include <hip/hip_bf16.h>

// T=256, B=4096, H=64.
// k1m : root MLP fully on MFMA. Per 16-row tile (1 wave, no barriers):
//       x->LDS (padded rows of 12), A1 frag with K-order k=(g4*4+d)+16h (zero-pad k>=9),
//       2 MFMA (layer1, N=32) -> relu -> pack pairs (p,p+16) -> LDS -> A2 b128 read ->
//       4 MFMA (layer2, N=64) -> relu -> bf16 hid [T*B][64] in d_ws (128 MB).
// k2m : 512 blocks x 8 batch elems, 5 waves (4 gate + 1 critic), double-buffered
//       hT2 -> ONE barrier/step. Elem rows 8-15 duplicate 0-7 (&7 clamp) so the
//       16x16 MFMA tiles stay valid with zero OOB. Critic pipelined one step behind.

#define TT 256
#define BB 4096
#define TBROWS (TT * BB)
#define LOG2E 1.44269504088896340736f

typedef short bf16x8 __attribute__((ext_vector_type(8)));
typedef float f32x4 __attribute__((ext_vector_type(4)));

__device__ __forceinline__ unsigned bfbits(float x) {  // f32 -> bf16 bits, RTNE
  unsigned u = __float_as_uint(x);
  return (u + 0x7fffu + ((u >> 16) & 1u)) >> 16;
}
__device__ __forceinline__ unsigned pkbf(float lo, float hi) {
  return bfbits(lo) | (bfbits(hi) << 16);
}
__device__ __forceinline__ float rcpf_(float x) { return __builtin_amdgcn_rcpf(x); }
__device__ __forceinline__ float exp2f_(float x) { return __builtin_amdgcn_exp2f(x); }

// ---------------- k1m: MFMA root MLP -> bf16 hid ----------------
// K-order for all frags here: dword d, half h, lane group g4: k = g4*4 + d + 16*h.
__global__ __launch_bounds__(256) void k1m(const float* __restrict__ x,
                                           const float* __restrict__ Wr1,
                                           const float* __restrict__ br1,
                                           const float* __restrict__ Wr2,
                                           const float* __restrict__ br2,
                                           unsigned short* __restrict__ hb) {
  __shared__ int sBr1[2 * 256];   // layer1 B frags (k>=9 zero-padded), 2 n-tiles
  __shared__ int sBr2[4 * 256];   // layer2 B frags, 4 n-tiles, pairs (p, p+16)
  __shared__ float sx[4][208];    // per-wave x staging, rows padded to 12
  __shared__ int h1s[4][324];     // per-wave h1 bf16-pair staging [row][p], stride 20

  const int tid = threadIdx.x;
  const int lane = tid & 63, wid = tid >> 6;
  const int g4 = lane >> 4, l15 = lane & 15;

  for (int i = tid; i < 512; i += 256) {
    int nt = i >> 8, rem = i & 255;
    int L = rem >> 2, d = rem & 3;
    int u = nt * 16 + (L & 15);
    int k0 = (L >> 4) * 4 + d;                     // k1 = k0+16 >= 16 > 8 -> 0
    float v0 = (k0 < 9) ? Wr1[k0 * 32 + u] : 0.f;
    sBr1[i] = (int)bfbits(v0);
  }
  for (int i = tid; i < 1024; i += 256) {
    int nt = i >> 8, rem = i & 255;
    int L = rem >> 2, d = rem & 3;
    int u = nt * 16 + (L & 15);
    int p = (L >> 4) * 4 + d;
    sBr2[i] = (int)pkbf(Wr2[p * 64 + u], Wr2[(p + 16) * 64 + u]);
  }
  __syncthreads();

  float br1v[2] = {br1[l15], br1[16 + l15]};
  float br2v[4];
#pragma unroll
  for (int nt = 0; nt < 4; ++nt) br2v[nt] = br2[nt * 16 + l15];

  long gw = (long)blockIdx.x * 4 + wid;
  long nw = (long)gridDim.x * 4;
  for (long row0 = gw * 16; row0 < TBROWS; row0 += nw * 16) {
    // stage 144 x-floats into padded rows (wave-local, DS in-order)
    {
      int j = lane;
      float v = x[row0 * 9 + j];
      int r = (j * 456) >> 12; int cc = j - r * 9;
      sx[wid][r * 12 + cc] = v;
      j = lane + 64;
      v = x[row0 * 9 + j];
      r = (j * 456) >> 12; cc = j - r * 9;
      sx[wid][r * 12 + cc] = v;
      if (lane < 16) {
        j = lane + 128;
        v = x[row0 * 9 + j];
        r = (j * 456) >> 12; cc = j - r * 9;
        sx[wid][r * 12 + cc] = v;
      }
    }
    // A1 fragment: row = l15, k0 = g4*4+d (<9 else 0), hi half always 0
    float4 xq = *(const float4*)&sx[wid][l15 * 12 + g4 * 4];
    union { unsigned u[4]; bf16x8 v; } A1;
#pragma unroll
    for (int d = 0; d < 4; ++d) {
      float v = ((const float*)&xq)[d];
      v = (g4 * 4 + d < 9) ? v : 0.f;
      A1.u[d] = bfbits(v);
    }
    f32x4 c1[2];
#pragma unroll
    for (int nt = 0; nt < 2; ++nt) {
      c1[nt] = (f32x4){br1v[nt], br1v[nt], br1v[nt], br1v[nt]};
      c1[nt] = __builtin_amdgcn_mfma_f32_16x16x32_bf16(
          A1.v, *(const bf16x8*)&sBr1[nt * 256 + lane * 4], c1[nt], 0, 0, 0);
    }
    // relu + pack pairs (p, p+16) -> h1s[row][p]
#pragma unroll
    for (int r = 0; r < 4; ++r)
      h1s[wid][(g4 * 4 + r) * 20 + l15] =
          (int)pkbf(fmaxf(c1[0][r], 0.f), fmaxf(c1[1][r], 0.f));
    // A2: one b128 per lane
    bf16x8 A2 = *(const bf16x8*)&h1s[wid][l15 * 20 + g4 * 4];
    f32x4 c2[4];
#pragma unroll
    for (int nt = 0; nt < 4; ++nt) {
      c2[nt] = (f32x4){br2v[nt], br2v[nt], br2v[nt], br2v[nt]};
      c2[nt] = __builtin_amdgcn_mfma_f32_16x16x32_bf16(
          A2, *(const bf16x8*)&sBr2[nt * 256 + lane * 4], c2[nt], 0, 0, 0);
    }
#pragma unroll
    for (int nt = 0; nt < 4; ++nt)
#pragma unroll
      for (int r = 0; r < 4; ++r)
        hb[(row0 + g4 * 4 + r) * 64 + nt * 16 + l15] =
            (unsigned short)bfbits(fmaxf(c2[nt][r], 0.f));
  }
}

// ---------------- k2m: MFMA serial LSTM, 8 elems/block, 1 barrier/step ----------------
// C layout (m89): col = lane&15, row = (lane>>4)*4 + reg.
__global__ __launch_bounds__(320) void k2m(
    const unsigned short* __restrict__ hb, const int* __restrict__ done,
    const float* __restrict__ h0, const float* __restrict__ c0,
    const float* __restrict__ Wih, const float* __restrict__ Whh,
    const float* __restrict__ bl,
    const float* __restrict__ Wc1, const float* __restrict__ bc1,
    const float* __restrict__ Wc2, const float* __restrict__ bc2,
    const float* __restrict__ Wc3, const float* __restrict__ bc3,
    float* __restrict__ out) {
  __shared__ int sBih[8192];      // 16 nt x 2 q x 64 lanes x 4 dwords (bf16 pairs)
  __shared__ int sBhh[8192];
  __shared__ int sBc1[512];       // critic Wc1 frags, scaled 2*log2e
  __shared__ __align__(16) unsigned short hT2[2][16 * 72];  // double-buffered h
  __shared__ float sv1[16 * 20];
  __shared__ float sWc2[128];

  const int tid = threadIdx.x;
  const int lane = tid & 63;
  const int wid = tid >> 6;
  const int g4 = lane >> 4, l15 = lane & 15;
  const int base_b = blockIdx.x * 8;

  for (int dwi = tid; dwi < 8192; dwi += 320) {
    int f = dwi >> 8, rem = dwi & 255;
    int L = rem >> 2, dd = rem & 3;
    int nt = f >> 1, q = f & 1;
    int k0 = q * 32 + (L >> 4) * 8 + 2 * dd;
    int col = nt * 16 + (L & 15);
    float sc = ((nt >> 2) == 2) ? 2.f * LOG2E : LOG2E;
    sBih[dwi] = (int)pkbf(Wih[k0 * 256 + col] * sc, Wih[(k0 + 1) * 256 + col] * sc);
    sBhh[dwi] = (int)pkbf(Whh[k0 * 256 + col] * sc, Whh[(k0 + 1) * 256 + col] * sc);
  }
  for (int dwi = tid; dwi < 512; dwi += 320) {
    int q = dwi >> 8, rem = dwi & 255;
    int L = rem >> 2, dd = rem & 3;
    int k0 = q * 32 + (L >> 4) * 8 + 2 * dd;
    int col = L & 15;
    float S = 2.f * LOG2E;
    sBc1[dwi] = (int)pkbf(Wc1[k0 * 16 + col] * S, Wc1[(k0 + 1) * 16 + col] * S);
  }
  for (int i = tid; i < 128; i += 320) sWc2[i] = Wc2[i] * 2.f * LOG2E;

  float c[4], bias_g[4];
  if (wid < 4) {
#pragma unroll
    for (int g = 0; g < 4; ++g) {
      float sc = (g == 2) ? 2.f * LOG2E : LOG2E;
      bias_g[g] = bl[(g * 4 + wid) * 16 + l15] * sc;
    }
#pragma unroll
    for (int r = 0; r < 4; ++r) {
      int row = base_b + ((g4 * 4 + r) & 7);   // rows 8-15 duplicate 0-7
      float m0 = 1.f - (float)done[row];
      c[r] = c0[row * 64 + wid * 16 + l15] * m0;
      hT2[1][(g4 * 4 + r) * 72 + wid * 16 + l15] =
          (unsigned short)bfbits(h0[row * 64 + wid * 16 + l15]);
    }
  }
  float bc1s = 0.f, bc2s0 = 0.f, bc2s1 = 0.f, wc3a = 0.f, wc3b = 0.f, bc3r = 0.f;
  if (wid == 4) {
    bc1s = bc1[l15] * 2.f * LOG2E;
    bc2s0 = bc2[g4 * 2] * 2.f * LOG2E;
    bc2s1 = bc2[g4 * 2 + 1] * 2.f * LOG2E;
    wc3a = Wc3[g4 * 2];
    wc3b = Wc3[g4 * 2 + 1];
    bc3r = bc3[0];
  }
  __syncthreads();

  bf16x8 aih0 = {}, aih1 = {};
  int dn_a = 0;
  const bf16x8* pB[4][4];
  if (wid < 4) {
    long rowA = base_b + (l15 & 7);
    aih0 = *(const bf16x8*)(hb + rowA * 64 + g4 * 8);
    aih1 = *(const bf16x8*)(hb + rowA * 64 + 32 + g4 * 8);
    dn_a = done[rowA];
#pragma unroll
    for (int g = 0; g < 4; ++g) {
      int nt = g * 4 + wid;
      pB[g][0] = (const bf16x8*)&sBih[(nt * 2 + 0) * 256 + lane * 4];
      pB[g][1] = (const bf16x8*)&sBih[(nt * 2 + 1) * 256 + lane * 4];
      pB[g][2] = (const bf16x8*)&sBhh[(nt * 2 + 0) * 256 + lane * 4];
      pB[g][3] = (const bf16x8*)&sBhh[(nt * 2 + 1) * 256 + lane * 4];
    }
  }

  auto critic_step = [&](int tprev, const unsigned short* rb) {
    bf16x8 ca0 = *(const bf16x8*)(rb + l15 * 72 + g4 * 8);
    bf16x8 ca1 = *(const bf16x8*)(rb + l15 * 72 + 32 + g4 * 8);
    f32x4 a1 = (f32x4){bc1s, bc1s, bc1s, bc1s};
    a1 = __builtin_amdgcn_mfma_f32_16x16x32_bf16(ca0, *(const bf16x8*)&sBc1[0 * 256 + lane * 4], a1, 0, 0, 0);
    a1 = __builtin_amdgcn_mfma_f32_16x16x32_bf16(ca1, *(const bf16x8*)&sBc1[1 * 256 + lane * 4], a1, 0, 0, 0);
#pragma unroll
    for (int r = 0; r < 4; ++r) {
      float v1 = fmaf(2.f, rcpf_(1.f + exp2f_(-a1[r])), -1.f);
      sv1[(g4 * 4 + r) * 20 + l15] = v1;
    }
    float a2a = bc2s0, a2b = bc2s1;
    const float* vrow = &sv1[l15 * 20];
#pragma unroll
    for (int k = 0; k < 16; ++k) {
      float vk = vrow[k];
      a2a = fmaf(vk, sWc2[k * 8 + g4 * 2], a2a);
      a2b = fmaf(vk, sWc2[k * 8 + g4 * 2 + 1], a2b);
    }
    float v2a = fmaf(2.f, rcpf_(1.f + exp2f_(-a2a)), -1.f);
    float v2b = fmaf(2.f, rcpf_(1.f + exp2f_(-a2b)), -1.f);
    float p = fmaf(v2a, wc3a, v2b * wc3b);
    p += __shfl_xor(p, 16);
    p += __shfl_xor(p, 32);
    if (g4 == 0 && l15 < 8) out[(long)tprev * BB + base_b + l15] = p + bc3r;
  };

  for (int t = 0; t < TT; ++t) {
    const unsigned short* rb = hT2[(t + 1) & 1];  // holds h_{t-1}
    unsigned short* wb = hT2[t & 1];
    if (wid < 4) {
      int4 r0 = *(const int4*)(rb + l15 * 72 + g4 * 8);
      int4 r1 = *(const int4*)(rb + l15 * 72 + 32 + g4 * 8);
      if (dn_a != 0) { r0 = make_int4(0, 0, 0, 0); r1 = make_int4(0, 0, 0, 0); }
      union { int4 i4; bf16x8 v; } ah0, ah1;
      ah0.i4 = r0; ah1.i4 = r1;

      bf16x8 nx0 = aih0, nx1 = aih1;
      int dn_a_nx = 0, dnc_nx[4] = {0, 0, 0, 0};
      if (t + 1 < TT) {
        long nb = ((long)(t + 1) * BB + base_b + (l15 & 7)) * 64;
        nx0 = *(const bf16x8*)(hb + nb + g4 * 8);
        nx1 = *(const bf16x8*)(hb + nb + 32 + g4 * 8);
        dn_a_nx = done[(long)(t + 1) * BB + base_b + (l15 & 7)];
#pragma unroll
        for (int r = 0; r < 4; ++r)
          dnc_nx[r] = done[(long)(t + 1) * BB + base_b + ((g4 * 4 + r) & 7)];
      }

      f32x4 acc[4];
#pragma unroll
      for (int g = 0; g < 4; ++g)
        acc[g] = (f32x4){bias_g[g], bias_g[g], bias_g[g], bias_g[g]};
#pragma unroll
      for (int g = 0; g < 4; ++g)
        acc[g] = __builtin_amdgcn_mfma_f32_16x16x32_bf16(aih0, *pB[g][0], acc[g], 0, 0, 0);
#pragma unroll
      for (int g = 0; g < 4; ++g)
        acc[g] = __builtin_amdgcn_mfma_f32_16x16x32_bf16(aih1, *pB[g][1], acc[g], 0, 0, 0);
#pragma unroll
      for (int g = 0; g < 4; ++g)
        acc[g] = __builtin_amdgcn_mfma_f32_16x16x32_bf16(ah0.v, *pB[g][2], acc[g], 0, 0, 0);
#pragma unroll
      for (int g = 0; g < 4; ++g)
        acc[g] = __builtin_amdgcn_mfma_f32_16x16x32_bf16(ah1.v, *pB[g][3], acc[g], 0, 0, 0);

      float out_h[4];
#pragma unroll
      for (int r = 0; r < 4; ++r) {
        float xi = acc[0][r], xf = acc[1][r], xg = acc[2][r], xo = acc[3][r];
        float si = rcpf_(1.f + exp2f_(-xi));
        float sf = rcpf_(1.f + exp2f_(-xf));
        float so = rcpf_(1.f + exp2f_(-xo));
        float tg = fmaf(2.f, rcpf_(1.f + exp2f_(-xg)), -1.f);
        float cc = fmaf(sf, c[r], si * tg);
        float tc = fmaf(2.f, rcpf_(1.f + exp2f_(cc * (-2.f * LOG2E))), -1.f);
        out_h[r] = so * tc;
        c[r] = cc * (1.f - (float)dnc_nx[r]);  // mask for t+1
      }
#pragma unroll
      for (int r = 0; r < 4; ++r)
        wb[(g4 * 4 + r) * 72 + wid * 16 + l15] = (unsigned short)bfbits(out_h[r]);

      aih0 = nx0; aih1 = nx1; dn_a = dn_a_nx;
    } else {
      if (t > 0) critic_step(t - 1, rb);
    }
    __syncthreads();  // single barrier per step (double-buffered hT2)
  }
  if (wid == 4) critic_step(TT - 1, hT2[(TT - 1) & 1]);
}

extern "C" void kernel_launch(void* const* d_in, const int* in_sizes, int n_in,
                              void* d_out, int out_size, void* d_ws, size_t ws_size,
                              hipStream_t stream) {
  const float* x = (const float*)d_in[0];
  const int* done = (const int*)d_in[1];
  const float* h0 = (const float*)d_in[2];
  const float* c0 = (const float*)d_in[3];
  const float* Wr1 = (const float*)d_in[4];
  const float* br1 = (const float*)d_in[5];
  const float* Wr2 = (const float*)d_in[6];
  const float* br2 = (const float*)d_in[7];
  const float* Wih = (const float*)d_in[8];
  const float* Whh = (const float*)d_in[9];
  const float* bl = (const float*)d_in[10];
  const float* Wc1 = (const float*)d_in[11];
  const float* bc1 = (const float*)d_in[12];
  const float* Wc2 = (const float*)d_in[13];
  const float* bc2 = (const float*)d_in[14];
  const float* Wc3 = (const float*)d_in[15];
  const float* bc3 = (const float*)d_in[16];
  float* out = (float*)d_out;

  unsigned short* hb = (unsigned short*)d_ws;  // 128 MB bf16 hid (read-only after k1m)

  k1m<<<dim3(1024), dim3(256), 0, stream>>>(x, Wr1, br1, Wr2, br2, hb);
  k2m<<<dim3(512), dim3(320), 0, stream>>>(hb, done, h0, c0, Wih, Whh, bl,
                                           Wc1, bc1, Wc2, bc2, Wc3, bc3, out);
}

// Round 6
// 666.486 us; speedup vs baseline: 1.1303x; 1.1303x over previous
//
#include <hip/hip_runtime.h>
#include <hip/hip_bf16.h>

// T=256, B=4096, H=64.
// k1m : root MLP fully on MFMA (unchanged from R5; verified absmax 2.4e-4).
// k2m : 512 blocks x 8 batch elems, 5 waves (4 gate + 1 critic).
//       ALL weight B-fragments live in VGPRs (loaded once per wave from global)
//       -> LDS is only hT2 double-buffer + sv1 (~6.5 KB) so 2 blocks/CU
//       co-reside (launch_bounds(320,3) caps VGPR at ~168 -> 12 waves/CU).
//       One barrier/step; critic wave pipelined one step behind.

#define TT 256
#define BB 4096
#define TBROWS (TT * BB)
#define LOG2E 1.44269504088896340736f

typedef short bf16x8 __attribute__((ext_vector_type(8)));
typedef float f32x4 __attribute__((ext_vector_type(4)));

__device__ __forceinline__ unsigned bfbits(float x) {  // f32 -> bf16 bits, RTNE
  unsigned u = __float_as_uint(x);
  return (u + 0x7fffu + ((u >> 16) & 1u)) >> 16;
}
__device__ __forceinline__ unsigned pkbf(float lo, float hi) {
  return bfbits(lo) | (bfbits(hi) << 16);
}
__device__ __forceinline__ float rcpf_(float x) { return __builtin_amdgcn_rcpf(x); }
__device__ __forceinline__ float exp2f_(float x) { return __builtin_amdgcn_exp2f(x); }

// ---------------- k1m: MFMA root MLP -> bf16 hid (unchanged from R5) ----------------
__global__ __launch_bounds__(256) void k1m(const float* __restrict__ x,
                                           const float* __restrict__ Wr1,
                                           const float* __restrict__ br1,
                                           const float* __restrict__ Wr2,
                                           const float* __restrict__ br2,
                                           unsigned short* __restrict__ hb) {
  __shared__ int sBr1[2 * 256];
  __shared__ int sBr2[4 * 256];
  __shared__ float sx[4][208];
  __shared__ int h1s[4][324];

  const int tid = threadIdx.x;
  const int lane = tid & 63, wid = tid >> 6;
  const int g4 = lane >> 4, l15 = lane & 15;

  for (int i = tid; i < 512; i += 256) {
    int nt = i >> 8, rem = i & 255;
    int L = rem >> 2, d = rem & 3;
    int u = nt * 16 + (L & 15);
    int k0 = (L >> 4) * 4 + d;
    float v0 = (k0 < 9) ? Wr1[k0 * 32 + u] : 0.f;
    sBr1[i] = (int)bfbits(v0);
  }
  for (int i = tid; i < 1024; i += 256) {
    int nt = i >> 8, rem = i & 255;
    int L = rem >> 2, d = rem & 3;
    int u = nt * 16 + (L & 15);
    int p = (L >> 4) * 4 + d;
    sBr2[i] = (int)pkbf(Wr2[p * 64 + u], Wr2[(p + 16) * 64 + u]);
  }
  __syncthreads();

  float br1v[2] = {br1[l15], br1[16 + l15]};
  float br2v[4];
#pragma unroll
  for (int nt = 0; nt < 4; ++nt) br2v[nt] = br2[nt * 16 + l15];

  long gw = (long)blockIdx.x * 4 + wid;
  long nw = (long)gridDim.x * 4;
  for (long row0 = gw * 16; row0 < TBROWS; row0 += nw * 16) {
    {
      int j = lane;
      float v = x[row0 * 9 + j];
      int r = (j * 456) >> 12; int cc = j - r * 9;
      sx[wid][r * 12 + cc] = v;
      j = lane + 64;
      v = x[row0 * 9 + j];
      r = (j * 456) >> 12; cc = j - r * 9;
      sx[wid][r * 12 + cc] = v;
      if (lane < 16) {
        j = lane + 128;
        v = x[row0 * 9 + j];
        r = (j * 456) >> 12; cc = j - r * 9;
        sx[wid][r * 12 + cc] = v;
      }
    }
    float4 xq = *(const float4*)&sx[wid][l15 * 12 + g4 * 4];
    union { unsigned u[4]; bf16x8 v; } A1;
#pragma unroll
    for (int d = 0; d < 4; ++d) {
      float v = ((const float*)&xq)[d];
      v = (g4 * 4 + d < 9) ? v : 0.f;
      A1.u[d] = bfbits(v);
    }
    f32x4 c1[2];
#pragma unroll
    for (int nt = 0; nt < 2; ++nt) {
      c1[nt] = (f32x4){br1v[nt], br1v[nt], br1v[nt], br1v[nt]};
      c1[nt] = __builtin_amdgcn_mfma_f32_16x16x32_bf16(
          A1.v, *(const bf16x8*)&sBr1[nt * 256 + lane * 4], c1[nt], 0, 0, 0);
    }
#pragma unroll
    for (int r = 0; r < 4; ++r)
      h1s[wid][(g4 * 4 + r) * 20 + l15] =
          (int)pkbf(fmaxf(c1[0][r], 0.f), fmaxf(c1[1][r], 0.f));
    bf16x8 A2 = *(const bf16x8*)&h1s[wid][l15 * 20 + g4 * 4];
    f32x4 c2[4];
#pragma unroll
    for (int nt = 0; nt < 4; ++nt) {
      c2[nt] = (f32x4){br2v[nt], br2v[nt], br2v[nt], br2v[nt]};
      c2[nt] = __builtin_amdgcn_mfma_f32_16x16x32_bf16(
          A2, *(const bf16x8*)&sBr2[nt * 256 + lane * 4], c2[nt], 0, 0, 0);
    }
#pragma unroll
    for (int nt = 0; nt < 4; ++nt)
#pragma unroll
      for (int r = 0; r < 4; ++r)
        hb[(row0 + g4 * 4 + r) * 64 + nt * 16 + l15] =
            (unsigned short)bfbits(fmaxf(c2[nt][r], 0.f));
  }
}

// ---------------- k2m: MFMA serial LSTM, register weights, tiny LDS ----------------
// C layout (m89): col = lane&15, row = (lane>>4)*4 + reg.
// Gate wave w: nt = g*4+w -> unit j = 16w + (lane&15), gate g.
__global__ __launch_bounds__(320, 3) void k2m(
    const unsigned short* __restrict__ hb, const int* __restrict__ done,
    const float* __restrict__ h0, const float* __restrict__ c0,
    const float* __restrict__ Wih, const float* __restrict__ Whh,
    const float* __restrict__ bl,
    const float* __restrict__ Wc1, const float* __restrict__ bc1,
    const float* __restrict__ Wc2, const float* __restrict__ bc2,
    const float* __restrict__ Wc3, const float* __restrict__ bc3,
    float* __restrict__ out) {
  __shared__ __align__(16) unsigned short hT2[2][16 * 72];  // double-buffered h (unmasked)
  __shared__ float sv1[16 * 20];                            // critic v1 bounce

  const int tid = threadIdx.x;
  const int lane = tid & 63;
  const int wid = tid >> 6;
  const int g4 = lane >> 4, l15 = lane & 15;
  const int base_b = blockIdx.x * 8;

  // ---- per-wave register weight fragments ----
  // k-order (shared by A and B builds): k0 = q*32 + (lane>>4)*8 + 2*d (+1 for hi half)
  union frag { unsigned u[4]; bf16x8 v; };
  frag Bih[4][2], Bhh[4][2];   // gate waves: [g][q]
  frag Bc1[2];                 // critic wave: [q]
  float wc2a[16], wc2b[16];    // critic wave Wc2 rows (scaled)
  float c[4], bias_g[4];
  float bc1s = 0.f, bc2s0 = 0.f, bc2s1 = 0.f, wc3a = 0.f, wc3b = 0.f, bc3r = 0.f;

  if (wid < 4) {
#pragma unroll
    for (int g = 0; g < 4; ++g) {
      int nt = g * 4 + wid;
      int col = nt * 16 + l15;
      float sc = (g == 2) ? 2.f * LOG2E : LOG2E;
#pragma unroll
      for (int q = 0; q < 2; ++q)
#pragma unroll
        for (int d = 0; d < 4; ++d) {
          int k0 = q * 32 + g4 * 8 + 2 * d;
          Bih[g][q].u[d] = pkbf(Wih[k0 * 256 + col] * sc, Wih[(k0 + 1) * 256 + col] * sc);
          Bhh[g][q].u[d] = pkbf(Whh[k0 * 256 + col] * sc, Whh[(k0 + 1) * 256 + col] * sc);
        }
      bias_g[g] = bl[nt * 16 + l15] * sc;
    }
#pragma unroll
    for (int r = 0; r < 4; ++r) {
      int row = base_b + ((g4 * 4 + r) & 7);   // rows 8-15 duplicate 0-7
      float m0 = 1.f - (float)done[row];
      c[r] = c0[row * 64 + wid * 16 + l15] * m0;
      hT2[1][(g4 * 4 + r) * 72 + wid * 16 + l15] =
          (unsigned short)bfbits(h0[row * 64 + wid * 16 + l15]);
    }
  } else {
    float S = 2.f * LOG2E;
#pragma unroll
    for (int q = 0; q < 2; ++q)
#pragma unroll
      for (int d = 0; d < 4; ++d) {
        int k0 = q * 32 + g4 * 8 + 2 * d;
        Bc1[q].u[d] = pkbf(Wc1[k0 * 16 + l15] * S, Wc1[(k0 + 1) * 16 + l15] * S);
      }
#pragma unroll
    for (int k = 0; k < 16; ++k) {
      wc2a[k] = Wc2[k * 8 + g4 * 2] * S;
      wc2b[k] = Wc2[k * 8 + g4 * 2 + 1] * S;
    }
    bc1s = bc1[l15] * S;
    bc2s0 = bc2[g4 * 2] * S;
    bc2s1 = bc2[g4 * 2 + 1] * S;
    wc3a = Wc3[g4 * 2];
    wc3b = Wc3[g4 * 2 + 1];
    bc3r = bc3[0];
  }
  __syncthreads();

  bf16x8 aih0 = {}, aih1 = {};
  int dn_a = 0;
  if (wid < 4) {
    long rowA = base_b + (l15 & 7);
    aih0 = *(const bf16x8*)(hb + rowA * 64 + g4 * 8);
    aih1 = *(const bf16x8*)(hb + rowA * 64 + 32 + g4 * 8);
    dn_a = done[rowA];
  }

  auto critic_step = [&](int tprev, const unsigned short* rb) {
    bf16x8 ca0 = *(const bf16x8*)(rb + l15 * 72 + g4 * 8);
    bf16x8 ca1 = *(const bf16x8*)(rb + l15 * 72 + 32 + g4 * 8);
    f32x4 a1 = (f32x4){bc1s, bc1s, bc1s, bc1s};
    a1 = __builtin_amdgcn_mfma_f32_16x16x32_bf16(ca0, Bc1[0].v, a1, 0, 0, 0);
    a1 = __builtin_amdgcn_mfma_f32_16x16x32_bf16(ca1, Bc1[1].v, a1, 0, 0, 0);
#pragma unroll
    for (int r = 0; r < 4; ++r) {
      float v1 = fmaf(2.f, rcpf_(1.f + exp2f_(-a1[r])), -1.f);
      sv1[(g4 * 4 + r) * 20 + l15] = v1;
    }
    float a2a = bc2s0, a2b = bc2s1;
    const float* vrow = &sv1[l15 * 20];
#pragma unroll
    for (int k = 0; k < 16; ++k) {
      float vk = vrow[k];
      a2a = fmaf(vk, wc2a[k], a2a);
      a2b = fmaf(vk, wc2b[k], a2b);
    }
    float v2a = fmaf(2.f, rcpf_(1.f + exp2f_(-a2a)), -1.f);
    float v2b = fmaf(2.f, rcpf_(1.f + exp2f_(-a2b)), -1.f);
    float p = fmaf(v2a, wc3a, v2b * wc3b);
    p += __shfl_xor(p, 16);
    p += __shfl_xor(p, 32);
    if (g4 == 0 && l15 < 8) out[(long)tprev * BB + base_b + l15] = p + bc3r;
  };

  for (int t = 0; t < TT; ++t) {
    const unsigned short* rb = hT2[(t + 1) & 1];  // h_{t-1}
    unsigned short* wb = hT2[t & 1];
    if (wid < 4) {
      int4 r0 = *(const int4*)(rb + l15 * 72 + g4 * 8);
      int4 r1 = *(const int4*)(rb + l15 * 72 + 32 + g4 * 8);
      if (dn_a != 0) { r0 = make_int4(0, 0, 0, 0); r1 = make_int4(0, 0, 0, 0); }
      union { int4 i4; bf16x8 v; } ah0, ah1;
      ah0.i4 = r0; ah1.i4 = r1;

      bf16x8 nx0 = aih0, nx1 = aih1;
      int dn_a_nx = 0, dnc_nx[4] = {0, 0, 0, 0};
      if (t + 1 < TT) {
        long nb = ((long)(t + 1) * BB + base_b + (l15 & 7)) * 64;
        nx0 = *(const bf16x8*)(hb + nb + g4 * 8);
        nx1 = *(const bf16x8*)(hb + nb + 32 + g4 * 8);
        dn_a_nx = done[(long)(t + 1) * BB + base_b + (l15 & 7)];
#pragma unroll
        for (int r = 0; r < 4; ++r)
          dnc_nx[r] = done[(long)(t + 1) * BB + base_b + ((g4 * 4 + r) & 7)];
      }

      f32x4 acc[4];
#pragma unroll
      for (int g = 0; g < 4; ++g)
        acc[g] = (f32x4){bias_g[g], bias_g[g], bias_g[g], bias_g[g]};
#pragma unroll
      for (int g = 0; g < 4; ++g)
        acc[g] = __builtin_amdgcn_mfma_f32_16x16x32_bf16(aih0, Bih[g][0].v, acc[g], 0, 0, 0);
#pragma unroll
      for (int g = 0; g < 4; ++g)
        acc[g] = __builtin_amdgcn_mfma_f32_16x16x32_bf16(aih1, Bih[g][1].v, acc[g], 0, 0, 0);
#pragma unroll
      for (int g = 0; g < 4; ++g)
        acc[g] = __builtin_amdgcn_mfma_f32_16x16x32_bf16(ah0.v, Bhh[g][0].v, acc[g], 0, 0, 0);
#pragma unroll
      for (int g = 0; g < 4; ++g)
        acc[g] = __builtin_amdgcn_mfma_f32_16x16x32_bf16(ah1.v, Bhh[g][1].v, acc[g], 0, 0, 0);

      float out_h[4];
#pragma unroll
      for (int r = 0; r < 4; ++r) {
        float xi = acc[0][r], xf = acc[1][r], xg = acc[2][r], xo = acc[3][r];
        float si = rcpf_(1.f + exp2f_(-xi));
        float sf = rcpf_(1.f + exp2f_(-xf));
        float so = rcpf_(1.f + exp2f_(-xo));
        float tg = fmaf(2.f, rcpf_(1.f + exp2f_(-xg)), -1.f);
        float cc = fmaf(sf, c[r], si * tg);
        float tc = fmaf(2.f, rcpf_(1.f + exp2f_(cc * (-2.f * LOG2E))), -1.f);
        out_h[r] = so * tc;
        c[r] = cc * (1.f - (float)dnc_nx[r]);  // mask for t+1
      }
#pragma unroll
      for (int r = 0; r < 4; ++r)
        wb[(g4 * 4 + r) * 72 + wid * 16 + l15] = (unsigned short)bfbits(out_h[r]);

      aih0 = nx0; aih1 = nx1; dn_a = dn_a_nx;
    } else {
      if (t > 0) critic_step(t - 1, rb);
    }
    __syncthreads();  // single barrier per step (double-buffered hT2)
  }
  if (wid == 4) critic_step(TT - 1, hT2[(TT - 1) & 1]);
}

extern "C" void kernel_launch(void* const* d_in, const int* in_sizes, int n_in,
                              void* d_out, int out_size, void* d_ws, size_t ws_size,
                              hipStream_t stream) {
  const float* x = (const float*)d_in[0];
  const int* done = (const int*)d_in[1];
  const float* h0 = (const float*)d_in[2];
  const float* c0 = (const float*)d_in[3];
  const float* Wr1 = (const float*)d_in[4];
  const float* br1 = (const float*)d_in[5];
  const float* Wr2 = (const float*)d_in[6];
  const float* br2 = (const float*)d_in[7];
  const float* Wih = (const float*)d_in[8];
  const float* Whh = (const float*)d_in[9];
  const float* bl = (const float*)d_in[10];
  const float* Wc1 = (const float*)d_in[11];
  const float* bc1 = (const float*)d_in[12];
  const float* Wc2 = (const float*)d_in[13];
  const float* bc2 = (const float*)d_in[14];
  const float* Wc3 = (const float*)d_in[15];
  const float* bc3 = (const float*)d_in[16];
  float* out = (float*)d_out;

  unsigned short* hb = (unsigned short*)d_ws;  // 128 MB bf16 hid (read-only after k1m)

  k1m<<<dim3(1024), dim3(256), 0, stream>>>(x, Wr1, br1, Wr2, br2, hb);
  k2m<<<dim3(512), dim3(320), 0, stream>>>(hb, done, h0, c0, Wih, Whh, bl,
                                           Wc1, bc1, Wc2, bc2, Wc3, bc3, out);
}

// Round 7
// 344.979 us; speedup vs baseline: 2.1837x; 1.9320x over previous
//
#include <hip/hip_runtime.h>
#include <hip/hip_bf16.h>

// T=256, B=4096, H=64.
// k1m : root MLP fully on MFMA (unchanged; verified absmax 2.4e-4).
// k2m : 256 blocks x 16 batch elems, 5 waves (4 gate + 1 critic) — R4's proven
//       geometry, with the measured stall sources removed:
//       - weight B-fragments in VGPRs (R6)
//       - done[] preloaded to LDS once (was 5 global loads/wave/step)
//       - hb prefetch issued at step TOP (vmcnt wait sinks to step bottom)
//       - MFMA chains split 2x2 instead of 4-deep
//       - double-buffered hT2, ONE barrier/step

#define TT 256
#define BB 4096
#define TBROWS (TT * BB)
#define LOG2E 1.44269504088896340736f

typedef short bf16x8 __attribute__((ext_vector_type(8)));
typedef float f32x4 __attribute__((ext_vector_type(4)));

__device__ __forceinline__ unsigned bfbits(float x) {  // f32 -> bf16 bits, RTNE
  unsigned u = __float_as_uint(x);
  return (u + 0x7fffu + ((u >> 16) & 1u)) >> 16;
}
__device__ __forceinline__ unsigned pkbf(float lo, float hi) {
  return bfbits(lo) | (bfbits(hi) << 16);
}
__device__ __forceinline__ float rcpf_(float x) { return __builtin_amdgcn_rcpf(x); }
__device__ __forceinline__ float exp2f_(float x) { return __builtin_amdgcn_exp2f(x); }

// ---------------- k1m: MFMA root MLP -> bf16 hid (unchanged from R5) ----------------
__global__ __launch_bounds__(256) void k1m(const float* __restrict__ x,
                                           const float* __restrict__ Wr1,
                                           const float* __restrict__ br1,
                                           const float* __restrict__ Wr2,
                                           const float* __restrict__ br2,
                                           unsigned short* __restrict__ hb) {
  __shared__ int sBr1[2 * 256];
  __shared__ int sBr2[4 * 256];
  __shared__ float sx[4][208];
  __shared__ int h1s[4][324];

  const int tid = threadIdx.x;
  const int lane = tid & 63, wid = tid >> 6;
  const int g4 = lane >> 4, l15 = lane & 15;

  for (int i = tid; i < 512; i += 256) {
    int nt = i >> 8, rem = i & 255;
    int L = rem >> 2, d = rem & 3;
    int u = nt * 16 + (L & 15);
    int k0 = (L >> 4) * 4 + d;
    float v0 = (k0 < 9) ? Wr1[k0 * 32 + u] : 0.f;
    sBr1[i] = (int)bfbits(v0);
  }
  for (int i = tid; i < 1024; i += 256) {
    int nt = i >> 8, rem = i & 255;
    int L = rem >> 2, d = rem & 3;
    int u = nt * 16 + (L & 15);
    int p = (L >> 4) * 4 + d;
    sBr2[i] = (int)pkbf(Wr2[p * 64 + u], Wr2[(p + 16) * 64 + u]);
  }
  __syncthreads();

  float br1v[2] = {br1[l15], br1[16 + l15]};
  float br2v[4];
#pragma unroll
  for (int nt = 0; nt < 4; ++nt) br2v[nt] = br2[nt * 16 + l15];

  long gw = (long)blockIdx.x * 4 + wid;
  long nw = (long)gridDim.x * 4;
  for (long row0 = gw * 16; row0 < TBROWS; row0 += nw * 16) {
    {
      int j = lane;
      float v = x[row0 * 9 + j];
      int r = (j * 456) >> 12; int cc = j - r * 9;
      sx[wid][r * 12 + cc] = v;
      j = lane + 64;
      v = x[row0 * 9 + j];
      r = (j * 456) >> 12; cc = j - r * 9;
      sx[wid][r * 12 + cc] = v;
      if (lane < 16) {
        j = lane + 128;
        v = x[row0 * 9 + j];
        r = (j * 456) >> 12; cc = j - r * 9;
        sx[wid][r * 12 + cc] = v;
      }
    }
    float4 xq = *(const float4*)&sx[wid][l15 * 12 + g4 * 4];
    union { unsigned u[4]; bf16x8 v; } A1;
#pragma unroll
    for (int d = 0; d < 4; ++d) {
      float v = ((const float*)&xq)[d];
      v = (g4 * 4 + d < 9) ? v : 0.f;
      A1.u[d] = bfbits(v);
    }
    f32x4 c1[2];
#pragma unroll
    for (int nt = 0; nt < 2; ++nt) {
      c1[nt] = (f32x4){br1v[nt], br1v[nt], br1v[nt], br1v[nt]};
      c1[nt] = __builtin_amdgcn_mfma_f32_16x16x32_bf16(
          A1.v, *(const bf16x8*)&sBr1[nt * 256 + lane * 4], c1[nt], 0, 0, 0);
    }
#pragma unroll
    for (int r = 0; r < 4; ++r)
      h1s[wid][(g4 * 4 + r) * 20 + l15] =
          (int)pkbf(fmaxf(c1[0][r], 0.f), fmaxf(c1[1][r], 0.f));
    bf16x8 A2 = *(const bf16x8*)&h1s[wid][l15 * 20 + g4 * 4];
    f32x4 c2[4];
#pragma unroll
    for (int nt = 0; nt < 4; ++nt) {
      c2[nt] = (f32x4){br2v[nt], br2v[nt], br2v[nt], br2v[nt]};
      c2[nt] = __builtin_amdgcn_mfma_f32_16x16x32_bf16(
          A2, *(const bf16x8*)&sBr2[nt * 256 + lane * 4], c2[nt], 0, 0, 0);
    }
#pragma unroll
    for (int nt = 0; nt < 4; ++nt)
#pragma unroll
      for (int r = 0; r < 4; ++r)
        hb[(row0 + g4 * 4 + r) * 64 + nt * 16 + l15] =
            (unsigned short)bfbits(fmaxf(c2[nt][r], 0.f));
  }
}

// ---------------- k2m: MFMA serial LSTM ----------------
// C layout (m89): col = lane&15, row = (lane>>4)*4 + reg.
// Gate wave w: nt = g*4+w -> unit j = 16w + (lane&15), gate g.
__global__ __launch_bounds__(320, 3) void k2m(
    const unsigned short* __restrict__ hb, const int* __restrict__ done,
    const float* __restrict__ h0, const float* __restrict__ c0,
    const float* __restrict__ Wih, const float* __restrict__ Whh,
    const float* __restrict__ bl,
    const float* __restrict__ Wc1, const float* __restrict__ bc1,
    const float* __restrict__ Wc2, const float* __restrict__ bc2,
    const float* __restrict__ Wc3, const float* __restrict__ bc3,
    float* __restrict__ out) {
  __shared__ __align__(16) unsigned short hT2[2][16 * 72];  // double-buffered h (unmasked)
  __shared__ float sv1[16 * 20];                            // critic v1 bounce
  __shared__ int sdone[TT * 16];                            // done flags for this block (16 KB)

  const int tid = threadIdx.x;
  const int lane = tid & 63;
  const int wid = tid >> 6;
  const int g4 = lane >> 4, l15 = lane & 15;
  const int base_b = blockIdx.x * 16;

  // ---- preload done flags (once) ----
  for (int i = tid; i < TT * 16; i += 320)
    sdone[i] = done[(long)(i >> 4) * BB + base_b + (i & 15)];

  // ---- per-wave register weight fragments ----
  // k-order (shared by A and B builds): k0 = q*32 + (lane>>4)*8 + 2*d (+1 for hi half)
  union frag { unsigned u[4]; bf16x8 v; };
  frag Bih[4][2], Bhh[4][2];   // gate waves: [g][q]
  frag Bc1[2];                 // critic wave
  float wc2a[16], wc2b[16];
  float c[4], bias_g[4];
  float bc1s = 0.f, bc2s0 = 0.f, bc2s1 = 0.f, wc3a = 0.f, wc3b = 0.f, bc3r = 0.f;

  if (wid < 4) {
#pragma unroll
    for (int g = 0; g < 4; ++g) {
      int nt = g * 4 + wid;
      int col = nt * 16 + l15;
      float sc = (g == 2) ? 2.f * LOG2E : LOG2E;
#pragma unroll
      for (int q = 0; q < 2; ++q)
#pragma unroll
        for (int d = 0; d < 4; ++d) {
          int k0 = q * 32 + g4 * 8 + 2 * d;
          Bih[g][q].u[d] = pkbf(Wih[k0 * 256 + col] * sc, Wih[(k0 + 1) * 256 + col] * sc);
          Bhh[g][q].u[d] = pkbf(Whh[k0 * 256 + col] * sc, Whh[(k0 + 1) * 256 + col] * sc);
        }
      bias_g[g] = bl[nt * 16 + l15] * sc;
    }
#pragma unroll
    for (int r = 0; r < 4; ++r) {
      int row = base_b + g4 * 4 + r;
      float m0 = 1.f - (float)done[row];
      c[r] = c0[row * 64 + wid * 16 + l15] * m0;
      hT2[1][(g4 * 4 + r) * 72 + wid * 16 + l15] =
          (unsigned short)bfbits(h0[row * 64 + wid * 16 + l15]);
    }
  } else {
    float S = 2.f * LOG2E;
#pragma unroll
    for (int q = 0; q < 2; ++q)
#pragma unroll
      for (int d = 0; d < 4; ++d) {
        int k0 = q * 32 + g4 * 8 + 2 * d;
        Bc1[q].u[d] = pkbf(Wc1[k0 * 16 + l15] * S, Wc1[(k0 + 1) * 16 + l15] * S);
      }
#pragma unroll
    for (int k = 0; k < 16; ++k) {
      wc2a[k] = Wc2[k * 8 + g4 * 2] * S;
      wc2b[k] = Wc2[k * 8 + g4 * 2 + 1] * S;
    }
    bc1s = bc1[l15] * S;
    bc2s0 = bc2[g4 * 2] * S;
    bc2s1 = bc2[g4 * 2 + 1] * S;
    wc3a = Wc3[g4 * 2];
    wc3b = Wc3[g4 * 2 + 1];
    bc3r = bc3[0];
  }
  __syncthreads();

  bf16x8 aih0 = {}, aih1 = {};
  if (wid < 4) {
    long rowA = base_b + l15;
    aih0 = *(const bf16x8*)(hb + rowA * 64 + g4 * 8);
    aih1 = *(const bf16x8*)(hb + rowA * 64 + 32 + g4 * 8);
  }

  auto critic_step = [&](int tprev, const unsigned short* rb) {
    bf16x8 ca0 = *(const bf16x8*)(rb + l15 * 72 + g4 * 8);
    bf16x8 ca1 = *(const bf16x8*)(rb + l15 * 72 + 32 + g4 * 8);
    f32x4 a1 = (f32x4){bc1s, bc1s, bc1s, bc1s};
    a1 = __builtin_amdgcn_mfma_f32_16x16x32_bf16(ca0, Bc1[0].v, a1, 0, 0, 0);
    a1 = __builtin_amdgcn_mfma_f32_16x16x32_bf16(ca1, Bc1[1].v, a1, 0, 0, 0);
#pragma unroll
    for (int r = 0; r < 4; ++r) {
      float v1 = fmaf(2.f, rcpf_(1.f + exp2f_(-a1[r])), -1.f);
      sv1[(g4 * 4 + r) * 20 + l15] = v1;
    }
    float a2a = bc2s0, a2b = bc2s1;
    const float* vrow = &sv1[l15 * 20];
#pragma unroll
    for (int k = 0; k < 16; ++k) {
      float vk = vrow[k];
      a2a = fmaf(vk, wc2a[k], a2a);
      a2b = fmaf(vk, wc2b[k], a2b);
    }
    float v2a = fmaf(2.f, rcpf_(1.f + exp2f_(-a2a)), -1.f);
    float v2b = fmaf(2.f, rcpf_(1.f + exp2f_(-a2b)), -1.f);
    float p = fmaf(v2a, wc3a, v2b * wc3b);
    p += __shfl_xor(p, 16);
    p += __shfl_xor(p, 32);
    if (g4 == 0) out[(long)tprev * BB + base_b + l15] = p + bc3r;
  };

  for (int t = 0; t < TT; ++t) {
    const unsigned short* rb = hT2[(t + 1) & 1];  // h_{t-1}
    unsigned short* wb = hT2[t & 1];
    if (wid < 4) {
      // issue next-step global prefetch FIRST (wait sinks to step bottom)
      bf16x8 nx0 = aih0, nx1 = aih1;
      if (t + 1 < TT) {
        long nb = ((long)(t + 1) * BB + base_b + l15) * 64;
        nx0 = *(const bf16x8*)(hb + nb + g4 * 8);
        nx1 = *(const bf16x8*)(hb + nb + 32 + g4 * 8);
      }
      // A_hh from LDS, masked by done[t] (flag from LDS)
      int dn = sdone[t * 16 + l15];
      int4 r0 = *(const int4*)(rb + l15 * 72 + g4 * 8);
      int4 r1 = *(const int4*)(rb + l15 * 72 + 32 + g4 * 8);
      if (dn != 0) { r0 = make_int4(0, 0, 0, 0); r1 = make_int4(0, 0, 0, 0); }
      union { int4 i4; bf16x8 v; } ah0, ah1;
      ah0.i4 = r0; ah1.i4 = r1;

      // gates: two 2-deep chains per gate, summed
      f32x4 accP[4], accQ[4];
#pragma unroll
      for (int g = 0; g < 4; ++g) {
        accP[g] = (f32x4){bias_g[g], bias_g[g], bias_g[g], bias_g[g]};
        accQ[g] = (f32x4){0.f, 0.f, 0.f, 0.f};
      }
#pragma unroll
      for (int g = 0; g < 4; ++g) {
        accP[g] = __builtin_amdgcn_mfma_f32_16x16x32_bf16(aih0, Bih[g][0].v, accP[g], 0, 0, 0);
        accQ[g] = __builtin_amdgcn_mfma_f32_16x16x32_bf16(aih1, Bih[g][1].v, accQ[g], 0, 0, 0);
      }
#pragma unroll
      for (int g = 0; g < 4; ++g) {
        accP[g] = __builtin_amdgcn_mfma_f32_16x16x32_bf16(ah0.v, Bhh[g][0].v, accP[g], 0, 0, 0);
        accQ[g] = __builtin_amdgcn_mfma_f32_16x16x32_bf16(ah1.v, Bhh[g][1].v, accQ[g], 0, 0, 0);
      }

      float out_h[4];
#pragma unroll
      for (int r = 0; r < 4; ++r) {
        float xi = accP[0][r] + accQ[0][r];
        float xf = accP[1][r] + accQ[1][r];
        float xg = accP[2][r] + accQ[2][r];
        float xo = accP[3][r] + accQ[3][r];
        float si = rcpf_(1.f + exp2f_(-xi));
        float sf = rcpf_(1.f + exp2f_(-xf));
        float so = rcpf_(1.f + exp2f_(-xo));
        float tg = fmaf(2.f, rcpf_(1.f + exp2f_(-xg)), -1.f);
        float cc = fmaf(sf, c[r], si * tg);
        float tc = fmaf(2.f, rcpf_(1.f + exp2f_(cc * (-2.f * LOG2E))), -1.f);
        out_h[r] = so * tc;
        float mn = (t + 1 < TT) ? (1.f - (float)sdone[(t + 1) * 16 + g4 * 4 + r]) : 1.f;
        c[r] = cc * mn;  // mask for t+1
      }
#pragma unroll
      for (int r = 0; r < 4; ++r)
        wb[(g4 * 4 + r) * 72 + wid * 16 + l15] = (unsigned short)bfbits(out_h[r]);

      aih0 = nx0; aih1 = nx1;  // vmcnt wait lands here, ~full step of slack
    } else {
      if (t > 0) critic_step(t - 1, rb);
    }
    __syncthreads();  // single barrier per step (double-buffered hT2)
  }
  if (wid == 4) critic_step(TT - 1, hT2[(TT - 1) & 1]);
}

extern "C" void kernel_launch(void* const* d_in, const int* in_sizes, int n_in,
                              void* d_out, int out_size, void* d_ws, size_t ws_size,
                              hipStream_t stream) {
  const float* x = (const float*)d_in[0];
  const int* done = (const int*)d_in[1];
  const float* h0 = (const float*)d_in[2];
  const float* c0 = (const float*)d_in[3];
  const float* Wr1 = (const float*)d_in[4];
  const float* br1 = (const float*)d_in[5];
  const float* Wr2 = (const float*)d_in[6];
  const float* br2 = (const float*)d_in[7];
  const float* Wih = (const float*)d_in[8];
  const float* Whh = (const float*)d_in[9];
  const float* bl = (const float*)d_in[10];
  const float* Wc1 = (const float*)d_in[11];
  const float* bc1 = (const float*)d_in[12];
  const float* Wc2 = (const float*)d_in[13];
  const float* bc2 = (const float*)d_in[14];
  const float* Wc3 = (const float*)d_in[15];
  const float* bc3 = (const float*)d_in[16];
  float* out = (float*)d_out;

  unsigned short* hb = (unsigned short*)d_ws;  // 128 MB bf16 hid (read-only after k1m)

  k1m<<<dim3(1024), dim3(256), 0, stream>>>(x, Wr1, br1, Wr2, br2, hb);
  k2m<<<dim3(256), dim3(320), 0, stream>>>(hb, done, h0, c0, Wih, Whh, bl,
                                           Wc1, bc1, Wc2, bc2, Wc3, bc3, out);
}